// Round 3
// baseline (193.466 us; speedup 1.0000x reference)
//
#include <hip/hip_runtime.h>
#include <hip/hip_bf16.h>

// GATLayer: x[8,1024,128], e[8,1024,1024], H=8 dh=16, CLIP=10, FF=512.
// R3: no-LDS 16x16x32 GEMMs on pre-converted bf16 operands (prep kernel),
// attention with 16 waves/block (8 heads x 2 m-halves) + LDS combine.

typedef __attribute__((ext_vector_type(4)))  float  f32x4;
typedef __attribute__((ext_vector_type(16))) float  f32x16;
typedef __attribute__((ext_vector_type(8)))  __bf16 bf8v;

#define DEV static __device__ __forceinline__

DEV ushort f2bf(float f) {
  __hip_bfloat16 h = __float2bfloat16(f);
  return __builtin_bit_cast(ushort, h);
}

DEV uint pk2(float a, float b) {
  return (uint)f2bf(a) | ((uint)f2bf(b) << 16);
}

DEV f32x16 zero16() {
  f32x16 z;
#pragma unroll
  for (int i = 0; i < 16; ++i) z[i] = 0.0f;
  return z;
}

union PU {
  uint u[4];
  bf8v v;
};

// ---------------- kernel 0: prep (bf16 convert + weight transposes) -------
DEV void tr_w(const float* __restrict__ S, ushort* __restrict__ D,
              int N, int K, int idx) {
  // D[n][k] = bf16(S[k][n]); one thread handles 4 consecutive k.
  int kq = K >> 2;
  int n = idx / kq;
  int k = (idx - n * kq) << 2;
  ushort4 o;
  o.x = f2bf(S[(size_t)(k + 0) * N + n]);
  o.y = f2bf(S[(size_t)(k + 1) * N + n]);
  o.z = f2bf(S[(size_t)(k + 2) * N + n]);
  o.w = f2bf(S[(size_t)(k + 3) * N + n]);
  *(ushort4*)&D[(size_t)n * K + k] = o;
}

__global__ __launch_bounds__(256) void prep_kernel(
    const float* __restrict__ x,  const float* __restrict__ Wq,
    const float* __restrict__ Wk, const float* __restrict__ Wv,
    const float* __restrict__ Wo, const float* __restrict__ W1,
    const float* __restrict__ W2,
    ushort* __restrict__ xb,  ushort* __restrict__ Wqt,
    ushort* __restrict__ Wkt, ushort* __restrict__ Wvt,
    ushort* __restrict__ Wot, ushort* __restrict__ W1t,
    ushort* __restrict__ W2t) {
  const int bid = blockIdx.x, tid = threadIdx.x;
  if (bid < 1024) {
    // xb: 8192x128 f32 -> bf16, 4 elems/thread
    int base = (bid * 256 + tid) * 4;
    f32x4 v = *(const f32x4*)(x + base);
    ushort4 o = make_ushort4(f2bf(v.x), f2bf(v.y), f2bf(v.z), f2bf(v.w));
    *(ushort4*)&xb[base] = o;
  } else {
    int gi = (bid - 1024) * 256 + tid;
    if      (gi < 4096)  tr_w(Wq, Wqt, 128, 128, gi);
    else if (gi < 8192)  tr_w(Wk, Wkt, 128, 128, gi - 4096);
    else if (gi < 12288) tr_w(Wv, Wvt, 128, 128, gi - 8192);
    else if (gi < 16384) tr_w(Wo, Wot, 128, 128, gi - 12288);
    else if (gi < 32768) tr_w(W1, W1t, 512, 128, gi - 16384);
    else                 tr_w(W2, W2t, 128, 512, gi - 32768);
  }
}

// ---------------- no-LDS 16x16x32 GEMM wave-tile --------------------------
// A bf16 [M][K] row-major, Bt bf16 [N][K] row-major (B transposed).
// A-frag: row=lane&15, k=8*(lane>>4)+j (16B contiguous). C: col=lane&15,
// row=(lane>>4)*4+i.
template <int K>
DEV f32x4 gemm16(const ushort* __restrict__ A, const ushort* __restrict__ Bt,
                 int m0, int n0, int lane) {
  const int r = lane & 15, g = lane >> 4;
  const ushort* pa = A + (size_t)(m0 + r) * K + g * 8;
  const ushort* pb = Bt + (size_t)(n0 + r) * K + g * 8;
  f32x4 acc = {0.0f, 0.0f, 0.0f, 0.0f};
#pragma unroll
  for (int k0 = 0; k0 < K; k0 += 32) {
    bf8v a = *(const bf8v*)(pa + k0);
    bf8v b = *(const bf8v*)(pb + k0);
    acc = __builtin_amdgcn_mfma_f32_16x16x32_bf16(a, b, acc, 0, 0, 0);
  }
  return acc;
}

// ---------------- kernel 1: QKV projection --------------------------------
// 3 projs x 512 mt x 8 nt = 12288 wave-tiles; 4 waves/block -> 3072 blocks.
// Writes Q,K [B,H,N,16] bf16; V transposed [B,H,16,N] bf16.
__global__ __launch_bounds__(256) void proj_kernel(
    const ushort* __restrict__ xb,  const ushort* __restrict__ Wqt,
    const ushort* __restrict__ Wkt, const ushort* __restrict__ Wvt,
    ushort* __restrict__ Qb, ushort* __restrict__ Kb, ushort* __restrict__ Vt) {
  const int w = blockIdx.x * 4 + (threadIdx.x >> 6);
  const int lane = threadIdx.x & 63;
  const int p = w >> 12;            // which projection
  const int t = w & 4095;
  const int mt = t >> 3, nt = t & 7;
  const ushort* Wt = p == 0 ? Wqt : (p == 1 ? Wkt : Wvt);
  f32x4 acc = gemm16<128>(xb, Wt, mt * 16, nt * 16, lane);
  const int g = lane >> 4, col = lane & 15;
  const int h = nt, d = col;        // 16-wide n-tiles align with heads
  if (p < 2) {
    ushort* dst = p ? Kb : Qb;
#pragma unroll
    for (int i = 0; i < 4; ++i) {
      int m = mt * 16 + g * 4 + i;
      int bb = m >> 10, ns = m & 1023;
      dst[((size_t)(bb * 8 + h) * 1024 + ns) * 16 + d] = f2bf(acc[i]);
    }
  } else {
    int m0 = mt * 16 + g * 4;
    int bb = m0 >> 10, ns = m0 & 1023;
    ushort4 pk = make_ushort4(f2bf(acc[0]), f2bf(acc[1]),
                              f2bf(acc[2]), f2bf(acc[3]));
    *(ushort4*)&Vt[((size_t)(bb * 8 + h) * 16 + d) * 1024 + ns] = pk;
  }
}

// ---------------- kernel 2: fused attention -------------------------------
// grid = B*32 blocks, 1024 thr = 16 waves = 8 heads x 2 m-halves.
// Swapped QK^T (32x32x16): lane owns q=lane&31; tanh clip -> fixed-max
// softmax, additive partial sums combined through LDS.
__global__ __launch_bounds__(1024) void attn_kernel(
    const ushort* __restrict__ Qb, const ushort* __restrict__ Kb,
    const ushort* __restrict__ Vt, const float* __restrict__ e,
    ushort* __restrict__ AO) {
  __shared__ float lacc[8][64][20];   // padded stride: bank-spread, 16B align
  __shared__ float lsum[8][64];
  const int b = blockIdx.x >> 5, qt = blockIdx.x & 31;
  const int wv = threadIdx.x >> 6, lane = threadIdx.x & 63;
  const int h = wv & 7, mh = wv >> 3;
  const int lq = lane & 31, hi = lane >> 5;
  const int q0 = qt * 32;
  const ushort* Qh = Qb + (size_t)(b * 8 + h) * (1024 * 16);
  const ushort* Kh = Kb + (size_t)(b * 8 + h) * (1024 * 16);
  const ushort* Vh = Vt + (size_t)(b * 8 + h) * (16 * 1024);
  const float* erow = e + ((size_t)b * 1024 + q0 + lq) * 1024;

  const bf8v qf = *(const bf8v*)(Qh + (q0 + lq) * 16 + hi * 8);
  f32x16 acc = zero16();
  float ssum = 0.0f;
  const float C2 = 2.8853900817779268f;    // 2*log2(e)
  const float C1 = -28.853900817779268f;   // -20*log2(e)

#pragma unroll 2
  for (int mt = 0; mt < 16; ++mt) {
    const int mbase = mh * 512 + mt * 32;
    bf8v kf = *(const bf8v*)(Kh + (mbase + lq) * 16 + hi * 8);
    f32x16 s = __builtin_amdgcn_mfma_f32_32x32x16_bf16(kf, qf, zero16(), 0, 0, 0);
    f32x4 ev[4];
#pragma unroll
    for (int g = 0; g < 4; ++g)
      ev[g] = *(const f32x4*)(erow + mbase + 4 * hi + 8 * g);
    float p[16];
#pragma unroll
    for (int r = 0; r < 16; ++r) {
      float y = s[r] * 0.25f + ev[r >> 2][r & 3];
      // p = exp(10*tanh(y) - 10) = exp2(C1 / (1 + exp2(C2*y)))
      float z = __builtin_amdgcn_exp2f(C2 * y);
      float pp = __builtin_amdgcn_exp2f(C1 * __builtin_amdgcn_rcpf(1.0f + z));
      p[r] = pp;
      ssum += pp;
    }
    uint w[8], pw[8];
#pragma unroll
    for (int j = 0; j < 8; ++j) w[j] = pk2(p[2 * j], p[2 * j + 1]);
#pragma unroll
    for (int j = 0; j < 8; ++j) pw[j] = (uint)__shfl_xor((int)w[j], 32);
    PU a0, a1;
    a0.u[0] = hi ? pw[2] : w[0];
    a0.u[1] = hi ? pw[3] : w[1];
    a0.u[2] = hi ? w[2] : pw[0];
    a0.u[3] = hi ? w[3] : pw[1];
    a1.u[0] = hi ? pw[6] : w[4];
    a1.u[1] = hi ? pw[7] : w[5];
    a1.u[2] = hi ? w[6] : pw[4];
    a1.u[3] = hi ? w[7] : pw[5];
    PU v0, v1;
#pragma unroll
    for (int j = 0; j < 4; ++j) { v0.u[j] = 0; v1.u[j] = 0; }
    if (lq < 16) {
      v0.v = *(const bf8v*)(Vh + lq * 1024 + mbase + hi * 8);
      v1.v = *(const bf8v*)(Vh + lq * 1024 + mbase + 16 + hi * 8);
    }
    acc = __builtin_amdgcn_mfma_f32_32x32x16_bf16(a0.v, v0.v, acc, 0, 0, 0);
    acc = __builtin_amdgcn_mfma_f32_32x32x16_bf16(a1.v, v1.v, acc, 0, 0, 0);
  }

  if (mh) {
#pragma unroll
    for (int r = 0; r < 16; ++r) lacc[h][lane][r] = acc[r];
    lsum[h][lane] = ssum;
  }
  __syncthreads();
  if (!mh) {
#pragma unroll
    for (int r = 0; r < 16; ++r) acc[r] += lacc[h][lane][r];
    ssum += lsum[h][lane];
    float tot = ssum + __shfl_xor(ssum, 32);
#pragma unroll
    for (int r = 0; r < 16; ++r) {
      int qr = (r & 3) + 8 * (r >> 2) + 4 * hi;
      float dn = __shfl(tot, qr);
      if (lq < 16) {
        float o = acc[r] * __builtin_amdgcn_rcpf(dn);
        AO[((size_t)(b * 1024) + q0 + qr) * 128 + h * 16 + lq] = f2bf(o);
      }
    }
  }
}

// ---------------- kernel 3: Wo GEMM + residual 1 --------------------------
// 512 mt x 8 nt = 4096 wave-tiles -> 1024 blocks.
__global__ __launch_bounds__(256) void wo_res_kernel(
    const ushort* __restrict__ AO, const ushort* __restrict__ Wot,
    const float* __restrict__ x, const float* __restrict__ alpha1,
    float* __restrict__ X1, ushort* __restrict__ X1b) {
  const int w = blockIdx.x * 4 + (threadIdx.x >> 6);
  const int lane = threadIdx.x & 63;
  const int mt = w >> 3, nt = w & 7;
  f32x4 acc = gemm16<128>(AO, Wot, mt * 16, nt * 16, lane);
  const float a1 = *alpha1;
  const int g = lane >> 4, n = nt * 16 + (lane & 15);
#pragma unroll
  for (int i = 0; i < 4; ++i) {
    int m = mt * 16 + g * 4 + i;
    float v = x[(size_t)m * 128 + n] + a1 * acc[i];
    X1[(size_t)m * 128 + n] = v;
    X1b[(size_t)m * 128 + n] = f2bf(v);
  }
}

// ---------------- kernel 4: FFN layer 1 (relu) ----------------------------
// 512 mt x 32 nt = 16384 wave-tiles -> 4096 blocks.
__global__ __launch_bounds__(256) void ffn1_kernel(
    const ushort* __restrict__ X1b, const ushort* __restrict__ W1t,
    const float* __restrict__ b1, ushort* __restrict__ Hb) {
  const int w = blockIdx.x * 4 + (threadIdx.x >> 6);
  const int lane = threadIdx.x & 63;
  const int mt = w >> 5, nt = w & 31;
  f32x4 acc = gemm16<128>(X1b, W1t, mt * 16, nt * 16, lane);
  const int g = lane >> 4, n = nt * 16 + (lane & 15);
  const float bias = b1[n];
#pragma unroll
  for (int i = 0; i < 4; ++i) {
    int m = mt * 16 + g * 4 + i;
    float v = fmaxf(acc[i] + bias, 0.0f);
    Hb[(size_t)m * 512 + n] = f2bf(v);
  }
}

// ---------------- kernel 5: FFN layer 2 + residual 2 ----------------------
// 512 mt x 8 nt = 4096 wave-tiles -> 1024 blocks. K=512.
__global__ __launch_bounds__(256) void ffn2_kernel(
    const ushort* __restrict__ Hb, const ushort* __restrict__ W2t,
    const float* __restrict__ b2, const float* __restrict__ X1,
    const float* __restrict__ alpha2, float* __restrict__ out) {
  const int w = blockIdx.x * 4 + (threadIdx.x >> 6);
  const int lane = threadIdx.x & 63;
  const int mt = w >> 3, nt = w & 7;
  f32x4 acc = gemm16<512>(Hb, W2t, mt * 16, nt * 16, lane);
  const float a2 = *alpha2;
  const int g = lane >> 4, n = nt * 16 + (lane & 15);
  const float bias = b2[n];
#pragma unroll
  for (int i = 0; i < 4; ++i) {
    int m = mt * 16 + g * 4 + i;
    float v = X1[(size_t)m * 128 + n] + a2 * (acc[i] + bias);
    out[(size_t)m * 128 + n] = v;
  }
}

// ---------------- launcher -------------------------------------------------
extern "C" void kernel_launch(void* const* d_in, const int* in_sizes, int n_in,
                              void* d_out, int out_size, void* d_ws, size_t ws_size,
                              hipStream_t stream) {
  (void)in_sizes; (void)n_in; (void)out_size; (void)ws_size;
  const float* x  = (const float*)d_in[0];
  const float* e  = (const float*)d_in[1];
  const float* Wq = (const float*)d_in[2];
  const float* Wk = (const float*)d_in[3];
  const float* Wv = (const float*)d_in[4];
  const float* Wo = (const float*)d_in[5];
  const float* W1 = (const float*)d_in[6];
  const float* b1 = (const float*)d_in[7];
  const float* W2 = (const float*)d_in[8];
  const float* b2 = (const float*)d_in[9];
  const float* a1 = (const float*)d_in[10];
  const float* a2 = (const float*)d_in[11];
  float* out = (float*)d_out;

  char* ws = (char*)d_ws;
  ushort* Qb  = (ushort*)(ws);                      // 2 MB [B,H,N,16]
  ushort* Kb  = (ushort*)(ws + (2ull << 20));       // 2 MB
  ushort* Vt  = (ushort*)(ws + (4ull << 20));       // 2 MB [B,H,16,N]
  ushort* AO  = (ushort*)(ws + (6ull << 20));       // 2 MB [8192,128]
  float*  X1  = (float*) (ws + (8ull << 20));       // 4 MB f32
  ushort* X1b = (ushort*)(ws + (12ull << 20));      // 2 MB
  ushort* Hb  = (ushort*)(ws + (14ull << 20));      // 8 MB [8192,512]
  ushort* xb  = (ushort*)(ws + (22ull << 20));      // 2 MB [8192,128]
  ushort* Wqt = (ushort*)(ws + (24ull << 20));              // 32 KB each
  ushort* Wkt = (ushort*)(ws + (24ull << 20) + (32u << 10));
  ushort* Wvt = (ushort*)(ws + (24ull << 20) + (64u << 10));
  ushort* Wot = (ushort*)(ws + (24ull << 20) + (96u << 10));
  ushort* W1t = (ushort*)(ws + (24ull << 20) + (128u << 10)); // 128 KB
  ushort* W2t = (ushort*)(ws + (24ull << 20) + (256u << 10)); // 128 KB

  prep_kernel<<<1216, 256, 0, stream>>>(x, Wq, Wk, Wv, Wo, W1, W2,
                                        xb, Wqt, Wkt, Wvt, Wot, W1t, W2t);
  proj_kernel<<<3072, 256, 0, stream>>>(xb, Wqt, Wkt, Wvt, Qb, Kb, Vt);
  attn_kernel<<<256, 1024, 0, stream>>>(Qb, Kb, Vt, e, AO);
  wo_res_kernel<<<1024, 256, 0, stream>>>(AO, Wot, x, a1, X1, X1b);
  ffn1_kernel<<<4096, 256, 0, stream>>>(X1b, W1t, b1, Hb);
  ffn2_kernel<<<1024, 256, 0, stream>>>(Hb, W2t, b2, X1, a2, out);
}

// Round 6
// 173.358 us; speedup vs baseline: 1.1160x; 1.1160x over previous
//
#include <hip/hip_runtime.h>
#include <hip/hip_bf16.h>

// GATLayer: x[8,1024,128], e[8,1024,1024], H=8 dh=16, CLIP=10, FF=512.
// R4: 4 kernels: prep (bf16 convert/transpose) -> proj (no-LDS 16x16x32)
// -> attn (R3 + v_cvt_pk_bf16_f32) -> fused wo+res1+ffn1+ffn2+res2.

typedef __attribute__((ext_vector_type(4)))  float  f32x4;
typedef __attribute__((ext_vector_type(16))) float  f32x16;
typedef __attribute__((ext_vector_type(8)))  __bf16 bf8v;

#define DEV static __device__ __forceinline__

DEV ushort f2bf(float f) {
  __hip_bfloat16 h = __float2bfloat16(f);
  return __builtin_bit_cast(ushort, h);
}

DEV uint cvtpk(float lo, float hi) {
  uint r;
  asm("v_cvt_pk_bf16_f32 %0, %1, %2" : "=v"(r) : "v"(lo), "v"(hi));
  return r;
}

DEV f32x16 zero16() {
  f32x16 z;
#pragma unroll
  for (int i = 0; i < 16; ++i) z[i] = 0.0f;
  return z;
}

union PU {
  uint u[4];
  bf8v v;
};

// ---------------- kernel 0: prep (bf16 convert + weight transposes) -------
DEV void tr_w(const float* __restrict__ S, ushort* __restrict__ D,
              int N, int K, int idx) {
  // D[n][k] = bf16(S[k][n]); one thread handles 4 consecutive k.
  int kq = K >> 2;
  int n = idx / kq;
  int k = (idx - n * kq) << 2;
  ushort4 o;
  o.x = f2bf(S[(size_t)(k + 0) * N + n]);
  o.y = f2bf(S[(size_t)(k + 1) * N + n]);
  o.z = f2bf(S[(size_t)(k + 2) * N + n]);
  o.w = f2bf(S[(size_t)(k + 3) * N + n]);
  *(ushort4*)&D[(size_t)n * K + k] = o;
}

__global__ __launch_bounds__(256) void prep_kernel(
    const float* __restrict__ x,  const float* __restrict__ Wq,
    const float* __restrict__ Wk, const float* __restrict__ Wv,
    const float* __restrict__ Wo, const float* __restrict__ W1,
    const float* __restrict__ W2,
    ushort* __restrict__ xb,  ushort* __restrict__ Wqt,
    ushort* __restrict__ Wkt, ushort* __restrict__ Wvt,
    ushort* __restrict__ Wot, ushort* __restrict__ W1t,
    ushort* __restrict__ W2t) {
  const int bid = blockIdx.x, tid = threadIdx.x;
  if (bid < 1024) {
    // xb: 8192x128 f32 -> bf16, 4 elems/thread
    int base = (bid * 256 + tid) * 4;
    f32x4 v = *(const f32x4*)(x + base);
    ushort4 o = make_ushort4(f2bf(v.x), f2bf(v.y), f2bf(v.z), f2bf(v.w));
    *(ushort4*)&xb[base] = o;
  } else {
    int gi = (bid - 1024) * 256 + tid;
    if      (gi < 4096)  tr_w(Wq, Wqt, 128, 128, gi);
    else if (gi < 8192)  tr_w(Wk, Wkt, 128, 128, gi - 4096);
    else if (gi < 12288) tr_w(Wv, Wvt, 128, 128, gi - 8192);
    else if (gi < 16384) tr_w(Wo, Wot, 128, 128, gi - 12288);
    else if (gi < 32768) tr_w(W1, W1t, 512, 128, gi - 16384);
    else                 tr_w(W2, W2t, 128, 512, gi - 32768);
  }
}

// ---------------- no-LDS 16x16x32 GEMM wave-tile --------------------------
// A bf16 [M][K] row-major, Bt bf16 [N][K] row-major (B transposed).
// A-frag: row=lane&15, k=8*(lane>>4)+j. C: col=lane&15, row=(lane>>4)*4+i.
template <int K>
DEV f32x4 gemm16(const ushort* __restrict__ A, const ushort* __restrict__ Bt,
                 int m0, int n0, int lane) {
  const int r = lane & 15, g = lane >> 4;
  const ushort* pa = A + (size_t)(m0 + r) * K + g * 8;
  const ushort* pb = Bt + (size_t)(n0 + r) * K + g * 8;
  f32x4 acc = {0.0f, 0.0f, 0.0f, 0.0f};
#pragma unroll
  for (int k0 = 0; k0 < K; k0 += 32) {
    bf8v a = *(const bf8v*)(pa + k0);
    bf8v b = *(const bf8v*)(pb + k0);
    acc = __builtin_amdgcn_mfma_f32_16x16x32_bf16(a, b, acc, 0, 0, 0);
  }
  return acc;
}

// Same, but A-fragment comes from an LDS tile (row stride LDA ushorts).
template <int K, int LDA>
DEV f32x4 gemm16_a_lds(const ushort* As, const ushort* __restrict__ Bt,
                       int n0, int lane) {
  const int r = lane & 15, g = lane >> 4;
  const ushort* pa = As + r * LDA + g * 8;
  const ushort* pb = Bt + (size_t)(n0 + r) * K + g * 8;
  f32x4 acc = {0.0f, 0.0f, 0.0f, 0.0f};
#pragma unroll
  for (int k0 = 0; k0 < K; k0 += 32) {
    bf8v a = *(const bf8v*)(pa + k0);
    bf8v b = *(const bf8v*)(pb + k0);
    acc = __builtin_amdgcn_mfma_f32_16x16x32_bf16(a, b, acc, 0, 0, 0);
  }
  return acc;
}

// ---------------- kernel 1: QKV projection --------------------------------
// 3 projs x 512 mt x 8 nt = 12288 wave-tiles; 4 waves/block -> 3072 blocks.
// Writes Q,K [B,H,N,16] bf16; V transposed [B,H,16,N] bf16.
__global__ __launch_bounds__(256) void proj_kernel(
    const ushort* __restrict__ xb,  const ushort* __restrict__ Wqt,
    const ushort* __restrict__ Wkt, const ushort* __restrict__ Wvt,
    ushort* __restrict__ Qb, ushort* __restrict__ Kb, ushort* __restrict__ Vt) {
  const int w = blockIdx.x * 4 + (threadIdx.x >> 6);
  const int lane = threadIdx.x & 63;
  const int p = w >> 12;            // which projection
  const int t = w & 4095;
  const int mt = t >> 3, nt = t & 7;
  const ushort* Wt = p == 0 ? Wqt : (p == 1 ? Wkt : Wvt);
  f32x4 acc = gemm16<128>(xb, Wt, mt * 16, nt * 16, lane);
  const int g = lane >> 4, col = lane & 15;
  const int h = nt, d = col;        // 16-wide n-tiles align with heads
  if (p < 2) {
    ushort* dst = p ? Kb : Qb;
#pragma unroll
    for (int i = 0; i < 4; ++i) {
      int m = mt * 16 + g * 4 + i;
      int bb = m >> 10, ns = m & 1023;
      dst[((size_t)(bb * 8 + h) * 1024 + ns) * 16 + d] = f2bf(acc[i]);
    }
  } else {
    int m0 = mt * 16 + g * 4;
    int bb = m0 >> 10, ns = m0 & 1023;
    ushort4 pk = make_ushort4(f2bf(acc[0]), f2bf(acc[1]),
                              f2bf(acc[2]), f2bf(acc[3]));
    *(ushort4*)&Vt[((size_t)(bb * 8 + h) * 16 + d) * 1024 + ns] = pk;
  }
}

// ---------------- kernel 2: fused attention -------------------------------
// grid = B*32 blocks, 1024 thr = 16 waves = 8 heads x 2 m-halves.
// Swapped QK^T (32x32x16): lane owns q=lane&31; tanh clip -> fixed-max
// softmax, additive partial sums combined through LDS.
__global__ __launch_bounds__(1024) void attn_kernel(
    const ushort* __restrict__ Qb, const ushort* __restrict__ Kb,
    const ushort* __restrict__ Vt, const float* __restrict__ e,
    ushort* __restrict__ AO) {
  __shared__ float lacc[8][64][20];   // padded stride: bank-spread, 16B align
  __shared__ float lsum[8][64];
  const int b = blockIdx.x >> 5, qt = blockIdx.x & 31;
  const int wv = threadIdx.x >> 6, lane = threadIdx.x & 63;
  const int h = wv & 7, mh = wv >> 3;
  const int lq = lane & 31, hi = lane >> 5;
  const int q0 = qt * 32;
  const ushort* Qh = Qb + (size_t)(b * 8 + h) * (1024 * 16);
  const ushort* Kh = Kb + (size_t)(b * 8 + h) * (1024 * 16);
  const ushort* Vh = Vt + (size_t)(b * 8 + h) * (16 * 1024);
  const float* erow = e + ((size_t)b * 1024 + q0 + lq) * 1024;

  const bf8v qf = *(const bf8v*)(Qh + (q0 + lq) * 16 + hi * 8);
  f32x16 acc = zero16();
  float ssum = 0.0f;
  const float C2 = 2.8853900817779268f;    // 2*log2(e)
  const float C1 = -28.853900817779268f;   // -20*log2(e)

#pragma unroll 2
  for (int mt = 0; mt < 16; ++mt) {
    const int mbase = mh * 512 + mt * 32;
    bf8v kf = *(const bf8v*)(Kh + (mbase + lq) * 16 + hi * 8);
    f32x16 s = __builtin_amdgcn_mfma_f32_32x32x16_bf16(kf, qf, zero16(), 0, 0, 0);
    f32x4 ev[4];
#pragma unroll
    for (int g = 0; g < 4; ++g)
      ev[g] = *(const f32x4*)(erow + mbase + 4 * hi + 8 * g);
    float p[16];
#pragma unroll
    for (int r = 0; r < 16; ++r) {
      float y = s[r] * 0.25f + ev[r >> 2][r & 3];
      // p = exp(10*tanh(y) - 10) = exp2(C1 / (1 + exp2(C2*y)))
      float z = __builtin_amdgcn_exp2f(C2 * y);
      float pp = __builtin_amdgcn_exp2f(C1 * __builtin_amdgcn_rcpf(1.0f + z));
      p[r] = pp;
      ssum += pp;
    }
    uint w[8], pw[8];
#pragma unroll
    for (int j = 0; j < 8; ++j) w[j] = cvtpk(p[2 * j], p[2 * j + 1]);
#pragma unroll
    for (int j = 0; j < 8; ++j) pw[j] = (uint)__shfl_xor((int)w[j], 32);
    PU a0, a1;
    a0.u[0] = hi ? pw[2] : w[0];
    a0.u[1] = hi ? pw[3] : w[1];
    a0.u[2] = hi ? w[2] : pw[0];
    a0.u[3] = hi ? w[3] : pw[1];
    a1.u[0] = hi ? pw[6] : w[4];
    a1.u[1] = hi ? pw[7] : w[5];
    a1.u[2] = hi ? w[6] : pw[4];
    a1.u[3] = hi ? w[7] : pw[5];
    PU v0, v1;
#pragma unroll
    for (int j = 0; j < 4; ++j) { v0.u[j] = 0; v1.u[j] = 0; }
    if (lq < 16) {
      v0.v = *(const bf8v*)(Vh + lq * 1024 + mbase + hi * 8);
      v1.v = *(const bf8v*)(Vh + lq * 1024 + mbase + 16 + hi * 8);
    }
    acc = __builtin_amdgcn_mfma_f32_32x32x16_bf16(a0.v, v0.v, acc, 0, 0, 0);
    acc = __builtin_amdgcn_mfma_f32_32x32x16_bf16(a1.v, v1.v, acc, 0, 0, 0);
  }

  if (mh) {
#pragma unroll
    for (int r = 0; r < 16; ++r) lacc[h][lane][r] = acc[r];
    lsum[h][lane] = ssum;
  }
  __syncthreads();
  if (!mh) {
#pragma unroll
    for (int r = 0; r < 16; ++r) acc[r] += lacc[h][lane][r];
    ssum += lsum[h][lane];
    float tot = ssum + __shfl_xor(ssum, 32);
#pragma unroll
    for (int r = 0; r < 16; ++r) {
      int qr = (r & 3) + 8 * (r >> 2) + 4 * hi;
      float dn = __shfl(tot, qr);
      if (lq < 16) {
        float o = acc[r] * __builtin_amdgcn_rcpf(dn);
        AO[((size_t)(b * 1024) + q0 + qr) * 128 + h * 16 + lq] = f2bf(o);
      }
    }
  }
}

// ---------------- kernel 3: fused Wo+res1 -> FFN1(relu) -> FFN2+res2 ------
// grid = 512 blocks (one per 16-row m-tile), 512 thr = 8 waves.
// X1 (f32+bf16) and H (bf16) tiles live in LDS; weights stream from L2.
__global__ __launch_bounds__(512) void fused_ffn_kernel(
    const ushort* __restrict__ AO, const ushort* __restrict__ Wot,
    const float* __restrict__ x, const float* __restrict__ alpha1,
    const ushort* __restrict__ W1t, const float* __restrict__ b1,
    const ushort* __restrict__ W2t, const float* __restrict__ b2,
    const float* __restrict__ alpha2, float* __restrict__ out) {
  __shared__ float  X1f[16][132];
  __shared__ ushort X1b[16][136];
  __shared__ ushort Hs[16][520];
  const int mt = blockIdx.x;
  const int w = threadIdx.x >> 6, lane = threadIdx.x & 63;
  const int g = lane >> 4, col = lane & 15;
  const float a1 = *alpha1, a2 = *alpha2;

  // step 1: X1 = x + a1 * (AO @ Wo); wave w owns cols w*16..w*16+15
  {
    f32x4 acc = gemm16<128>(AO, Wot, mt * 16, w * 16, lane);
    int n = w * 16 + col;
#pragma unroll
    for (int i = 0; i < 4; ++i) {
      int row = g * 4 + i;
      float v = x[(size_t)(mt * 16 + row) * 128 + n] + a1 * acc[i];
      X1f[row][n] = v;
      X1b[row][n] = f2bf(v);
    }
  }
  __syncthreads();

  // step 2: H = relu(X1b @ W1 + b1); wave w owns cols w*64..w*64+63
#pragma unroll
  for (int j = 0; j < 4; ++j) {
    int n0 = w * 64 + j * 16;
    f32x4 acc = gemm16_a_lds<128, 136>(&X1b[0][0], W1t, n0, lane);
    int n = n0 + col;
    float bias = b1[n];
#pragma unroll
    for (int i = 0; i < 4; ++i) {
      int row = g * 4 + i;
      Hs[row][n] = f2bf(fmaxf(acc[i] + bias, 0.0f));
    }
  }
  __syncthreads();

  // step 3: out = X1 + a2 * (H @ W2 + b2); wave w owns cols w*16..w*16+15
  {
    f32x4 acc = gemm16_a_lds<512, 520>(&Hs[0][0], W2t, w * 16, lane);
    int n = w * 16 + col;
    float bias = b2[n];
#pragma unroll
    for (int i = 0; i < 4; ++i) {
      int row = g * 4 + i;
      out[(size_t)(mt * 16 + row) * 128 + n] =
          X1f[row][n] + a2 * (acc[i] + bias);
    }
  }
}

// ---------------- launcher -------------------------------------------------
extern "C" void kernel_launch(void* const* d_in, const int* in_sizes, int n_in,
                              void* d_out, int out_size, void* d_ws, size_t ws_size,
                              hipStream_t stream) {
  (void)in_sizes; (void)n_in; (void)out_size; (void)ws_size;
  const float* x  = (const float*)d_in[0];
  const float* e  = (const float*)d_in[1];
  const float* Wq = (const float*)d_in[2];
  const float* Wk = (const float*)d_in[3];
  const float* Wv = (const float*)d_in[4];
  const float* Wo = (const float*)d_in[5];
  const float* W1 = (const float*)d_in[6];
  const float* b1 = (const float*)d_in[7];
  const float* W2 = (const float*)d_in[8];
  const float* b2 = (const float*)d_in[9];
  const float* a1 = (const float*)d_in[10];
  const float* a2 = (const float*)d_in[11];
  float* out = (float*)d_out;

  char* ws = (char*)d_ws;
  ushort* Qb  = (ushort*)(ws);                      // 2 MB [B,H,N,16]
  ushort* Kb  = (ushort*)(ws + (2ull << 20));       // 2 MB
  ushort* Vt  = (ushort*)(ws + (4ull << 20));       // 2 MB [B,H,16,N]
  ushort* AO  = (ushort*)(ws + (6ull << 20));       // 2 MB [8192,128]
  ushort* xb  = (ushort*)(ws + (8ull << 20));       // 2 MB [8192,128]
  ushort* Wqt = (ushort*)(ws + (10ull << 20));              // 32 KB each
  ushort* Wkt = (ushort*)(ws + (10ull << 20) + (32u << 10));
  ushort* Wvt = (ushort*)(ws + (10ull << 20) + (64u << 10));
  ushort* Wot = (ushort*)(ws + (10ull << 20) + (96u << 10));
  ushort* W1t = (ushort*)(ws + (10ull << 20) + (128u << 10)); // 128 KB
  ushort* W2t = (ushort*)(ws + (10ull << 20) + (256u << 10)); // 128 KB

  prep_kernel<<<1216, 256, 0, stream>>>(x, Wq, Wk, Wv, Wo, W1, W2,
                                        xb, Wqt, Wkt, Wvt, Wot, W1t, W2t);
  proj_kernel<<<3072, 256, 0, stream>>>(xb, Wqt, Wkt, Wvt, Qb, Kb, Vt);
  attn_kernel<<<256, 1024, 0, stream>>>(Qb, Kb, Vt, e, AO);
  fused_ffn_kernel<<<512, 512, 0, stream>>>(AO, Wot, x, a1, W1t, b1,
                                            W2t, b2, a2, out);
}